// Round 7
// baseline (238.847 us; speedup 1.0000x reference)
//
#include <hip/hip_runtime.h>
#include <hip/hip_fp16.h>

#define N_NODES 50000
#define N_EDGES 800000
#define F_INN   128
#define F_HID   96
#define F_OUTT  40

typedef _Float16 half8 __attribute__((ext_vector_type(8)));
typedef float    floatx4 __attribute__((ext_vector_type(4)));

// ---------------------------------------------------------------------------
// Prep (fused): zero counts4 + weight transpose W[K x 96] -> BT[96][K] fp16.
// Blocks [0, ZB): memset. Blocks [ZB, ZB+WB): transpose.
// ---------------------------------------------------------------------------
#define ZB 196   // ceil(50000 int4 / 256)
#define WB 84    // ceil((96*128 + 96*96) / 256)

__global__ __launch_bounds__(256) void prep_kernel(
        int4* __restrict__ counts4, const float* __restrict__ W1,
        const float* __restrict__ W2, __half* __restrict__ BT1,
        __half* __restrict__ BT2) {
    int b = blockIdx.x;
    if (b < ZB) {
        int i = b * 256 + threadIdx.x;
        if (i < N_NODES) counts4[i] = make_int4(0, 0, 0, 0);
    } else {
        int i = (b - ZB) * 256 + threadIdx.x;
        if (i < 96 * 128) {
            int j = i / 128, k = i - j * 128;
            BT1[j * 128 + k] = __float2half(W1[k * 96 + j]);
        } else if (i < 96 * 128 + 96 * 96) {
            int t = i - 96 * 128;
            int j = t / 96, k = t - j * 96;
            BT2[j * 96 + k] = __float2half(W2[k * 96 + j]);
        }
    }
}

// ---------------------------------------------------------------------------
// Edge count: counts4[dst*4+shard]++ ; rank = slot within (dst,shard).
// 8 VGPR, 0 LDS -> full occupancy (latency-bound atomics need the waves).
// ---------------------------------------------------------------------------
__global__ void count_kernel(const int* __restrict__ dst, int* __restrict__ counts4,
                             int* __restrict__ rank, int e) {
    int i = blockIdx.x * blockDim.x + threadIdx.x;
    if (i < e) rank[i] = atomicAdd(&counts4[dst[i] * 4 + (i & 3)], 1);
}

// ---------------------------------------------------------------------------
// Scan phase 1: per-block exclusive scan of node degrees; dinv; block sums.
// ---------------------------------------------------------------------------
__global__ __launch_bounds__(1024) void scan_local_kernel(
        const int4* __restrict__ counts4, int* __restrict__ row_start,
        float* __restrict__ dinv, int* __restrict__ blk_sums, int n) {
    __shared__ int wave_sums[16];
    int tid = threadIdx.x, lane = tid & 63, wid = tid >> 6;
    int i = blockIdx.x * 1024 + tid;
    int v = 0;
    if (i < n) {
        int4 c = counts4[i];
        v = c.x + c.y + c.z + c.w;
    }
    int val = v;
    #pragma unroll
    for (int off = 1; off < 64; off <<= 1) {
        int u = __shfl_up(val, off, 64);
        if (lane >= off) val += u;
    }
    if (lane == 63) wave_sums[wid] = val;
    __syncthreads();
    if (wid == 0) {
        int w = (lane < 16) ? wave_sums[lane] : 0;
        #pragma unroll
        for (int off = 1; off < 16; off <<= 1) {
            int u = __shfl_up(w, off, 64);
            if (lane >= off) w += u;
        }
        if (lane < 16) wave_sums[lane] = w;
    }
    __syncthreads();
    int excl = ((wid == 0) ? 0 : wave_sums[wid - 1]) + (val - v);
    if (i < n) {
        row_start[i] = excl;                  // local; global offset in phase 2
        dinv[i] = rsqrtf((float)(v + 1));     // +1 self loop
    }
    if (tid == 0) blk_sums[blockIdx.x] = wave_sums[15];
}

// ---------------------------------------------------------------------------
// Scan phase 2+3 fused: every block redundantly scans the <=64 block sums,
// applies its own offset, emits per-shard bases base4. Block 0 writes total.
// ---------------------------------------------------------------------------
__global__ __launch_bounds__(1024) void scan_apply_kernel(
        int* __restrict__ row_start, const int* __restrict__ blk_sums,
        const int4* __restrict__ counts4, int4* __restrict__ base4, int n, int nblk) {
    __shared__ int s_my, s_tot;
    int tid = threadIdx.x;
    if (tid < 64) {
        int v = (tid < nblk) ? blk_sums[tid] : 0;
        int val = v;
        #pragma unroll
        for (int off = 1; off < 64; off <<= 1) {
            int u = __shfl_up(val, off, 64);
            if (tid >= off) val += u;
        }
        if (tid == (int)blockIdx.x) s_my = val - v;   // exclusive prefix
        if (tid == 63) s_tot = val;                   // grand total == E
    }
    __syncthreads();
    int i = blockIdx.x * 1024 + tid;
    if (i < n) {
        int4 c = counts4[i];
        int b = row_start[i] + s_my;
        row_start[i] = b;
        base4[i] = make_int4(b, b + c.x, b + c.x + c.y, b + c.x + c.y + c.z);
    }
    if (blockIdx.x == 0 && tid == 0) row_start[n] = s_tot;
}

// Atomic-free fill: pos = base4[dst].shard + rank.  One scattered 4B store.
__global__ void fill_csr_kernel(const int* __restrict__ src, const int* __restrict__ dst,
                                const int* __restrict__ rank, const int* __restrict__ base4,
                                int* __restrict__ csr_src, int e) {
    int i = blockIdx.x * blockDim.x + threadIdx.x;
    if (i >= e) return;
    csr_src[base4[dst[i] * 4 + (i & 3)] + rank[i]] = src[i];
}

// ---------------------------------------------------------------------------
// LDS-free MFMA GEMM: T[n][96] (fp16) = X[n x FI] @ W, via 16x16x32 f16.
// A = W^T tile (m=feature) loaded straight from global (24.5 KB -> L1-resident,
// same address across waves). B = node rows. D[feature][node]: lane (lm,q)
// holds features t*16+q*4..+3 of node lm -> direct int2 global stores, no LDS,
// no barriers. 4 waves x 16 nodes = 64 nodes/block.
// ---------------------------------------------------------------------------
template <int FI, typename TIN>
__device__ __forceinline__ void mfma_gemm_body(
        const TIN* __restrict__ X, const __half* __restrict__ BTg,   // [96][FI]
        __half* __restrict__ Th, int n, int bx) {
    int tid = threadIdx.x;
    int lane = tid & 63, w = tid >> 6;
    int lm = lane & 15, q = lane >> 4;
    int node = bx * 64 + w * 16 + lm;
    int nclamp = min(node, n - 1);
    const TIN* Xrow = X + (size_t)nclamp * FI;

    floatx4 cf[6];
    #pragma unroll
    for (int t = 0; t < 6; ++t) cf[t] = (floatx4){0.f, 0.f, 0.f, 0.f};

    constexpr int KS = FI / 32;
    #pragma unroll
    for (int ks = 0; ks < KS; ++ks) {
        // B-operand: lane holds k = 32*ks + q*8 .. +7 of its node's row
        half8 bv;
        if constexpr (sizeof(TIN) == 4) {
            const float4* xr = reinterpret_cast<const float4*>(Xrow + 32 * ks + q * 8);
            float4 f0 = xr[0], f1 = xr[1];
            union { half8 v; __half2 h[4]; } b;
            b.h[0] = __floats2half2_rn(f0.x, f0.y);
            b.h[1] = __floats2half2_rn(f0.z, f0.w);
            b.h[2] = __floats2half2_rn(f1.x, f1.y);
            b.h[3] = __floats2half2_rn(f1.z, f1.w);
            bv = b.v;
        } else {
            bv = *reinterpret_cast<const half8*>(Xrow + 32 * ks + q * 8);
        }
        #pragma unroll
        for (int t = 0; t < 6; ++t) {
            half8 a = *reinterpret_cast<const half8*>(
                BTg + (t * 16 + lm) * FI + 32 * ks + q * 8);
            cf[t] = __builtin_amdgcn_mfma_f32_16x16x32_f16(a, bv, cf[t], 0, 0, 0);
        }
    }

    if (node < n) {
        __half* orow = Th + (size_t)node * 96;
        #pragma unroll
        for (int t = 0; t < 6; ++t) {
            union { int2 i2; __half2 h[2]; } u;
            u.h[0] = __floats2half2_rn(cf[t][0], cf[t][1]);
            u.h[1] = __floats2half2_rn(cf[t][2], cf[t][3]);
            *reinterpret_cast<int2*>(orow + t * 16 + q * 4) = u.i2;
        }
    }
}

template <int FI, typename TIN>
__global__ __launch_bounds__(256) void mfma_gemm_kernel(
        const TIN* __restrict__ X, const __half* __restrict__ BTg,
        __half* __restrict__ Th, int n) {
    mfma_gemm_body<FI, TIN>(X, BTg, Th, n, blockIdx.x);
}

// ---------------------------------------------------------------------------
// Aggregation: one wave per node; T unscaled fp16; per-edge weight dinv[s] is
// a wave-uniform SCALAR load.  H[d] = relu(dinv[d]*(Σ dinv[s]T[s] + dinv[d]T[d]) + b)
// Output fp16.
// ---------------------------------------------------------------------------
__global__ __launch_bounds__(256) void agg_kernel(
        const __half2* __restrict__ T, const int* __restrict__ row_start,
        const int* __restrict__ csr_src, const float* __restrict__ dinv,
        const float* __restrict__ bias, __half2* __restrict__ H, int n) {
    int lane = threadIdx.x & 63;
    int node = __builtin_amdgcn_readfirstlane(blockIdx.x * 4 + (threadIdx.x >> 6));
    if (node >= n) return;
    int fl = min(lane, 47);                    // lanes 48..63 duplicate lane 47

    float dn = dinv[node];
    float2 self = __half22float2(T[(size_t)node * 48 + fl]);
    float accx = dn * self.x, accy = dn * self.y;   // dinv[d]*T[d]

    int idx = row_start[node];
    int end = row_start[node + 1];
    for (; idx + 8 <= end; idx += 8) {
        int s[8];
        #pragma unroll
        for (int u = 0; u < 8; ++u) s[u] = csr_src[idx + u];
        float ws[8];
        #pragma unroll
        for (int u = 0; u < 8; ++u) ws[u] = dinv[s[u]];          // scalar loads
        float2 f[8];
        #pragma unroll
        for (int u = 0; u < 8; ++u) f[u] = __half22float2(T[(size_t)s[u] * 48 + fl]);
        #pragma unroll
        for (int u = 0; u < 8; ++u) {
            accx = fmaf(ws[u], f[u].x, accx);
            accy = fmaf(ws[u], f[u].y, accy);
        }
    }
    for (; idx < end; ++idx) {
        int s = csr_src[idx];
        float w = dinv[s];
        float2 f = __half22float2(T[(size_t)s * 48 + fl]);
        accx = fmaf(w, f.x, accx);
        accy = fmaf(w, f.y, accy);
    }
    if (lane < 48) {
        float2 b = reinterpret_cast<const float2*>(bias)[lane];
        float ox = fmaxf(fmaf(dn, accx, b.x), 0.f);
        float oy = fmaxf(fmaf(dn, accy, b.y), 0.f);
        H[(size_t)node * 48 + lane] = __floats2half2_rn(ox, oy);
    }
}

// ---------------------------------------------------------------------------
// Output GEMM: out[n x 40] = H[n x 96](fp16) @ W[96 x 40] + bias (fp32 acc).
// ---------------------------------------------------------------------------
__global__ __launch_bounds__(320) void gemm_out_kernel(
        const __half2* __restrict__ A, const float* __restrict__ W,
        const float* __restrict__ bias, float* __restrict__ C, int n) {
    __shared__ float Wlds[96 * 40];
    int tid = threadIdx.y * 10 + threadIdx.x;
    for (int i = tid; i < 96 * 10; i += 320)
        reinterpret_cast<float4*>(Wlds)[i] = reinterpret_cast<const float4*>(W)[i];
    __syncthreads();

    int j    = threadIdx.x * 4;
    int node = blockIdx.x * 32 + threadIdx.y;
    int nc   = min(node, n - 1);
    const __half2* Ah = A + (size_t)nc * 48;
    float4 acc = make_float4(0.f, 0.f, 0.f, 0.f);
    for (int k2 = 0; k2 < 48; k2 += 2) {          // k = 2*k2 .. 2*k2+3
        float2 a01 = __half22float2(Ah[k2]);
        float2 a23 = __half22float2(Ah[k2 + 1]);
        int k = 2 * k2;
        float4 w0 = *reinterpret_cast<const float4*>(Wlds + (k + 0) * 40 + j);
        float4 w1 = *reinterpret_cast<const float4*>(Wlds + (k + 1) * 40 + j);
        float4 w2 = *reinterpret_cast<const float4*>(Wlds + (k + 2) * 40 + j);
        float4 w3 = *reinterpret_cast<const float4*>(Wlds + (k + 3) * 40 + j);
        acc.x += a01.x * w0.x + a01.y * w1.x + a23.x * w2.x + a23.y * w3.x;
        acc.y += a01.x * w0.y + a01.y * w1.y + a23.x * w2.y + a23.y * w3.y;
        acc.z += a01.x * w0.z + a01.y * w1.z + a23.x * w2.z + a23.y * w3.z;
        acc.w += a01.x * w0.w + a01.y * w1.w + a23.x * w2.w + a23.y * w3.w;
    }
    if (node < n) {
        float4 b = *reinterpret_cast<const float4*>(bias + j);
        acc.x += b.x; acc.y += b.y; acc.z += b.z; acc.w += b.w;
        *reinterpret_cast<float4*>(C + (size_t)node * 40 + j) = acc;
    }
}

// ---------------------------------------------------------------------------

extern "C" void kernel_launch(void* const* d_in, const int* in_sizes, int n_in,
                              void* d_out, int out_size, void* d_ws, size_t ws_size,
                              hipStream_t stream) {
    const float* x    = (const float*)d_in[0];
    const int*   ei   = (const int*)d_in[1];
    const float* W1   = (const float*)d_in[2];
    const float* b1   = (const float*)d_in[3];
    const float* W2   = (const float*)d_in[4];
    const float* b2   = (const float*)d_in[5];
    const float* Wout = (const float*)d_in[6];
    const float* bout = (const float*)d_in[7];
    float*       out  = (float*)d_out;

    const int* src = ei;            // edge_index[0]
    const int* dst = ei + N_EDGES;  // edge_index[1]

    char* ws = (char*)d_ws;
    size_t off = 0;
    auto alloc = [&](size_t bytes) {
        size_t o = off;
        off = (off + bytes + 511) & ~(size_t)511;
        return (void*)(ws + o);
    };
    int*     counts4   = (int*)    alloc((size_t)N_NODES * 4 * sizeof(int));
    int4*    base4     = (int4*)   alloc((size_t)N_NODES * sizeof(int4));
    int*     row_start = (int*)    alloc((N_NODES + 1) * sizeof(int));
    float*   dinv      = (float*)  alloc(N_NODES * sizeof(float));
    int*     blk_sums  = (int*)    alloc(64 * sizeof(int));
    int*     rank      = (int*)    alloc((size_t)N_EDGES * sizeof(int));
    int*     csr_src   = (int*)    alloc((size_t)N_EDGES * sizeof(int));
    __half*  BT1       = (__half*) alloc((size_t)96 * 128 * sizeof(__half));
    __half*  BT2       = (__half*) alloc((size_t)96 * 96 * sizeof(__half));
    __half*  Th        = (__half*) alloc((size_t)N_NODES * 96 * sizeof(__half));
    __half*  Hh        = (__half*) alloc((size_t)N_NODES * 96 * sizeof(__half));

    const int NSCAN = (N_NODES + 1023) / 1024;   // 49
    const int CB    = (N_EDGES + 255) / 256;     // 3125
    const int GB    = (N_NODES + 63) / 64;       // 782

    // --- prep: zero counts4 + transpose weights (one launch) ---
    prep_kernel<<<ZB + WB, 256, 0, stream>>>(
        (int4*)counts4, W1, W2, BT1, BT2);

    // --- CSR: count (full occupancy) -> scan x2 -> fill ---
    count_kernel<<<CB, 256, 0, stream>>>(dst, counts4, rank, N_EDGES);

    // --- layer-1 GEMM (depends only on prep; placed here to fill the gap) ---
    mfma_gemm_kernel<F_INN, float><<<GB, 256, 0, stream>>>(x, BT1, Th, N_NODES);

    scan_local_kernel<<<NSCAN, 1024, 0, stream>>>(
        (const int4*)counts4, row_start, dinv, blk_sums, N_NODES);
    scan_apply_kernel<<<NSCAN, 1024, 0, stream>>>(
        row_start, blk_sums, (const int4*)counts4, base4, N_NODES, NSCAN);
    fill_csr_kernel<<<CB, 256, 0, stream>>>(
        src, dst, rank, (const int*)base4, csr_src, N_EDGES);

    // --- layer 1 aggregation -> H (fp16) ---
    agg_kernel<<<(N_NODES + 3) / 4, 256, 0, stream>>>(
        (const __half2*)Th, row_start, csr_src, dinv, b1, (__half2*)Hh, N_NODES);

    // --- layer 2: GEMM (fp16 in) + aggregation ---
    mfma_gemm_kernel<F_HID, __half><<<GB, 256, 0, stream>>>(Hh, BT2, Th, N_NODES);
    agg_kernel<<<(N_NODES + 3) / 4, 256, 0, stream>>>(
        (const __half2*)Th, row_start, csr_src, dinv, b2, (__half2*)Hh, N_NODES);

    // --- output ---
    gemm_out_kernel<<<(N_NODES + 31) / 32, dim3(10, 32), 0, stream>>>(
        (const __half2*)Hh, Wout, bout, out, N_NODES);
}

// Round 8
// 229.946 us; speedup vs baseline: 1.0387x; 1.0387x over previous
//
#include <hip/hip_runtime.h>
#include <hip/hip_fp16.h>

#define N_NODES 50000
#define N_EDGES 800000
#define F_INN   128
#define F_HID   96
#define F_OUTT  40

typedef _Float16 half8 __attribute__((ext_vector_type(8)));
typedef float    floatx4 __attribute__((ext_vector_type(4)));

// ---------------------------------------------------------------------------
// Prep (fused): zero counts4 + weight transpose W[K x 96] -> BT[96][136] fp16
// (pad 8 halves). Blocks [0, ZB): memset. Blocks [ZB, ZB+WB): transpose.
// ---------------------------------------------------------------------------
#define ZB 196   // ceil(50000 int4 / 256)
#define WB 84    // ceil((96*128 + 96*96) / 256)

__global__ __launch_bounds__(256) void prep_kernel(
        int4* __restrict__ counts4, const float* __restrict__ W1,
        const float* __restrict__ W2, __half* __restrict__ BT1,
        __half* __restrict__ BT2) {
    int b = blockIdx.x;
    if (b < ZB) {
        int i = b * 256 + threadIdx.x;
        if (i < N_NODES) counts4[i] = make_int4(0, 0, 0, 0);
    } else {
        int i = (b - ZB) * 256 + threadIdx.x;
        if (i < 96 * 128) {
            int j = i / 128, k = i - j * 128;
            BT1[j * 136 + k] = __float2half(W1[k * 96 + j]);
        } else if (i < 96 * 128 + 96 * 96) {
            int t = i - 96 * 128;
            int j = t / 96, k = t - j * 96;
            BT2[j * 136 + k] = __float2half(W2[k * 96 + j]);
        }
    }
}

// ---------------------------------------------------------------------------
// Edge count: counts4[dst*4+shard]++ ; rank = slot within (dst,shard).
// 8 VGPR, 0 LDS -> full occupancy (latency-bound atomics need the waves).
// ---------------------------------------------------------------------------
__global__ void count_kernel(const int* __restrict__ dst, int* __restrict__ counts4,
                             int* __restrict__ rank, int e) {
    int i = blockIdx.x * blockDim.x + threadIdx.x;
    if (i < e) rank[i] = atomicAdd(&counts4[dst[i] * 4 + (i & 3)], 1);
}

// ---------------------------------------------------------------------------
// Scan phase 1: per-block exclusive scan of node degrees; dinv; block sums.
// ---------------------------------------------------------------------------
__global__ __launch_bounds__(1024) void scan_local_kernel(
        const int4* __restrict__ counts4, int* __restrict__ row_start,
        float* __restrict__ dinv, int* __restrict__ blk_sums, int n) {
    __shared__ int wave_sums[16];
    int tid = threadIdx.x, lane = tid & 63, wid = tid >> 6;
    int i = blockIdx.x * 1024 + tid;
    int v = 0;
    if (i < n) {
        int4 c = counts4[i];
        v = c.x + c.y + c.z + c.w;
    }
    int val = v;
    #pragma unroll
    for (int off = 1; off < 64; off <<= 1) {
        int u = __shfl_up(val, off, 64);
        if (lane >= off) val += u;
    }
    if (lane == 63) wave_sums[wid] = val;
    __syncthreads();
    if (wid == 0) {
        int w = (lane < 16) ? wave_sums[lane] : 0;
        #pragma unroll
        for (int off = 1; off < 16; off <<= 1) {
            int u = __shfl_up(w, off, 64);
            if (lane >= off) w += u;
        }
        if (lane < 16) wave_sums[lane] = w;
    }
    __syncthreads();
    int excl = ((wid == 0) ? 0 : wave_sums[wid - 1]) + (val - v);
    if (i < n) {
        row_start[i] = excl;                  // local; global offset in phase 2
        dinv[i] = rsqrtf((float)(v + 1));     // +1 self loop
    }
    if (tid == 0) blk_sums[blockIdx.x] = wave_sums[15];
}

// ---------------------------------------------------------------------------
// Scan phase 2+3 fused: every block redundantly scans the <=64 block sums,
// applies its own offset, emits per-shard bases base4. Block 0 writes total.
// ---------------------------------------------------------------------------
__global__ __launch_bounds__(1024) void scan_apply_kernel(
        int* __restrict__ row_start, const int* __restrict__ blk_sums,
        const int4* __restrict__ counts4, int4* __restrict__ base4, int n, int nblk) {
    __shared__ int s_my, s_tot;
    int tid = threadIdx.x;
    if (tid < 64) {
        int v = (tid < nblk) ? blk_sums[tid] : 0;
        int val = v;
        #pragma unroll
        for (int off = 1; off < 64; off <<= 1) {
            int u = __shfl_up(val, off, 64);
            if (tid >= off) val += u;
        }
        if (tid == (int)blockIdx.x) s_my = val - v;   // exclusive prefix
        if (tid == 63) s_tot = val;                   // grand total == E
    }
    __syncthreads();
    int i = blockIdx.x * 1024 + tid;
    if (i < n) {
        int4 c = counts4[i];
        int b = row_start[i] + s_my;
        row_start[i] = b;
        base4[i] = make_int4(b, b + c.x, b + c.x + c.y, b + c.x + c.y + c.z);
    }
    if (blockIdx.x == 0 && tid == 0) row_start[n] = s_tot;
}

// Atomic-free fill: pos = base4[dst].shard + rank.  One scattered 4B store.
__global__ void fill_csr_kernel(const int* __restrict__ src, const int* __restrict__ dst,
                                const int* __restrict__ rank, const int* __restrict__ base4,
                                int* __restrict__ csr_src, int e) {
    int i = blockIdx.x * blockDim.x + threadIdx.x;
    if (i >= e) return;
    csr_src[base4[dst[i] * 4 + (i & 3)] + rank[i]] = src[i];
}

// ---------------------------------------------------------------------------
// MFMA GEMM (round-6 proven LDS body): T[n][96] (fp16) = X[n x FI] @ W.
// A = W^T tile from LDS (staged once per block, 64x reuse), B = node rows.
// Epilogue transposes through per-wave LDS -> coalesced float4 stores.
// 4 waves x 16 nodes = 64 nodes/block.
// ---------------------------------------------------------------------------
template <int FI, typename TIN>
__device__ __forceinline__ void mfma_gemm_body(
        const TIN* __restrict__ X, const __half* __restrict__ BTg,  // [96][136]
        float4* __restrict__ Th4, int n, int bx) {
    __shared__ __half BTl[96 * 136];          // 26112 B
    __shared__ __half OUTl[4 * 16 * 104];     // 13312 B
    int tid = threadIdx.x;
    {   // stage BT (1632 x 16B)
        const int4* s = reinterpret_cast<const int4*>(BTg);
        int4* d = reinterpret_cast<int4*>(BTl);
        for (int i = tid; i < 96 * 136 / 8; i += 256) d[i] = s[i];
    }
    __syncthreads();

    int lane = tid & 63, w = tid >> 6;
    int lm = lane & 15, q = lane >> 4;
    int base = bx * 64 + w * 16;
    int node = base + lm;
    int nclamp = min(node, n - 1);
    const TIN* Xrow = X + (size_t)nclamp * FI;

    floatx4 cf[6];
    #pragma unroll
    for (int t = 0; t < 6; ++t) cf[t] = (floatx4){0.f, 0.f, 0.f, 0.f};

    constexpr int KS = FI / 32;
    #pragma unroll
    for (int ks = 0; ks < KS; ++ks) {
        // B-operand: lane holds k = 32*ks + q*8 .. +7 of its node's row
        half8 bv;
        if constexpr (sizeof(TIN) == 4) {
            const float4* xr = reinterpret_cast<const float4*>(Xrow + 32 * ks + q * 8);
            float4 f0 = xr[0], f1 = xr[1];
            union { half8 v; __half2 h[4]; } b;
            b.h[0] = __floats2half2_rn(f0.x, f0.y);
            b.h[1] = __floats2half2_rn(f0.z, f0.w);
            b.h[2] = __floats2half2_rn(f1.x, f1.y);
            b.h[3] = __floats2half2_rn(f1.z, f1.w);
            bv = b.v;
        } else {
            bv = *reinterpret_cast<const half8*>(Xrow + 32 * ks + q * 8);
        }
        #pragma unroll
        for (int t = 0; t < 6; ++t) {
            half8 a = *reinterpret_cast<const half8*>(
                &BTl[(t * 16 + lm) * 136 + q * 8 + 32 * ks]);
            cf[t] = __builtin_amdgcn_mfma_f32_16x16x32_f16(a, bv, cf[t], 0, 0, 0);
        }
    }

    // Epilogue: D[row=q*4+r][col=lm] = out[feature = t*16+q*4+r][node=lm].
    __half* orow = OUTl + (w * 16 + lm) * 104;
    #pragma unroll
    for (int t = 0; t < 6; ++t) {
        union { int2 i2; __half2 h[2]; } u;
        u.h[0] = __floats2half2_rn(cf[t][0], cf[t][1]);
        u.h[1] = __floats2half2_rn(cf[t][2], cf[t][3]);
        *reinterpret_cast<int2*>(&orow[t * 16 + q * 4]) = u.i2;
    }
    // Same-wave LDS round-trip: coalesced fp16 row store (12 x float4 per node).
    #pragma unroll
    for (int R = 0; R < 3; ++R) {
        int nl = lane >> 2, c = (lane & 3) + 4 * R;
        float4 v = *reinterpret_cast<const float4*>(&OUTl[(w * 16 + nl) * 104 + c * 8]);
        int gn = base + nl;
        if (gn < n) Th4[(size_t)gn * 12 + c] = v;
    }
}

template <int FI, typename TIN>
__global__ __launch_bounds__(256) void mfma_gemm_kernel(
        const TIN* __restrict__ X, const __half* __restrict__ BTg,
        float4* __restrict__ Th4, int n) {
    mfma_gemm_body<FI, TIN>(X, BTg, Th4, n, blockIdx.x);
}

// ---------------------------------------------------------------------------
// Aggregation: one wave per node; T unscaled fp16; per-edge weight dinv[s] is
// a wave-uniform SCALAR load.  H[d] = relu(dinv[d]*(Σ dinv[s]T[s] + dinv[d]T[d]) + b)
// Output fp16.
// ---------------------------------------------------------------------------
__global__ __launch_bounds__(256) void agg_kernel(
        const __half2* __restrict__ T, const int* __restrict__ row_start,
        const int* __restrict__ csr_src, const float* __restrict__ dinv,
        const float* __restrict__ bias, __half2* __restrict__ H, int n) {
    int lane = threadIdx.x & 63;
    int node = __builtin_amdgcn_readfirstlane(blockIdx.x * 4 + (threadIdx.x >> 6));
    if (node >= n) return;
    int fl = min(lane, 47);                    // lanes 48..63 duplicate lane 47

    float dn = dinv[node];
    float2 self = __half22float2(T[(size_t)node * 48 + fl]);
    float accx = dn * self.x, accy = dn * self.y;   // dinv[d]*T[d]

    int idx = row_start[node];
    int end = row_start[node + 1];
    for (; idx + 8 <= end; idx += 8) {
        int s[8];
        #pragma unroll
        for (int u = 0; u < 8; ++u) s[u] = csr_src[idx + u];
        float ws[8];
        #pragma unroll
        for (int u = 0; u < 8; ++u) ws[u] = dinv[s[u]];          // scalar loads
        float2 f[8];
        #pragma unroll
        for (int u = 0; u < 8; ++u) f[u] = __half22float2(T[(size_t)s[u] * 48 + fl]);
        #pragma unroll
        for (int u = 0; u < 8; ++u) {
            accx = fmaf(ws[u], f[u].x, accx);
            accy = fmaf(ws[u], f[u].y, accy);
        }
    }
    for (; idx < end; ++idx) {
        int s = csr_src[idx];
        float w = dinv[s];
        float2 f = __half22float2(T[(size_t)s * 48 + fl]);
        accx = fmaf(w, f.x, accx);
        accy = fmaf(w, f.y, accy);
    }
    if (lane < 48) {
        float2 b = reinterpret_cast<const float2*>(bias)[lane];
        float ox = fmaxf(fmaf(dn, accx, b.x), 0.f);
        float oy = fmaxf(fmaf(dn, accy, b.y), 0.f);
        H[(size_t)node * 48 + lane] = __floats2half2_rn(ox, oy);
    }
}

// ---------------------------------------------------------------------------
// Output GEMM: out[n x 40] = H[n x 96](fp16) @ W[96 x 40] + bias (fp32 acc).
// ---------------------------------------------------------------------------
__global__ __launch_bounds__(320) void gemm_out_kernel(
        const __half2* __restrict__ A, const float* __restrict__ W,
        const float* __restrict__ bias, float* __restrict__ C, int n) {
    __shared__ float Wlds[96 * 40];
    int tid = threadIdx.y * 10 + threadIdx.x;
    for (int i = tid; i < 96 * 10; i += 320)
        reinterpret_cast<float4*>(Wlds)[i] = reinterpret_cast<const float4*>(W)[i];
    __syncthreads();

    int j    = threadIdx.x * 4;
    int node = blockIdx.x * 32 + threadIdx.y;
    int nc   = min(node, n - 1);
    const __half2* Ah = A + (size_t)nc * 48;
    float4 acc = make_float4(0.f, 0.f, 0.f, 0.f);
    for (int k2 = 0; k2 < 48; k2 += 2) {          // k = 2*k2 .. 2*k2+3
        float2 a01 = __half22float2(Ah[k2]);
        float2 a23 = __half22float2(Ah[k2 + 1]);
        int k = 2 * k2;
        float4 w0 = *reinterpret_cast<const float4*>(Wlds + (k + 0) * 40 + j);
        float4 w1 = *reinterpret_cast<const float4*>(Wlds + (k + 1) * 40 + j);
        float4 w2 = *reinterpret_cast<const float4*>(Wlds + (k + 2) * 40 + j);
        float4 w3 = *reinterpret_cast<const float4*>(Wlds + (k + 3) * 40 + j);
        acc.x += a01.x * w0.x + a01.y * w1.x + a23.x * w2.x + a23.y * w3.x;
        acc.y += a01.x * w0.y + a01.y * w1.y + a23.x * w2.y + a23.y * w3.y;
        acc.z += a01.x * w0.z + a01.y * w1.z + a23.x * w2.z + a23.y * w3.z;
        acc.w += a01.x * w0.w + a01.y * w1.w + a23.x * w2.w + a23.y * w3.w;
    }
    if (node < n) {
        float4 b = *reinterpret_cast<const float4*>(bias + j);
        acc.x += b.x; acc.y += b.y; acc.z += b.z; acc.w += b.w;
        *reinterpret_cast<float4*>(C + (size_t)node * 40 + j) = acc;
    }
}

// ---------------------------------------------------------------------------

extern "C" void kernel_launch(void* const* d_in, const int* in_sizes, int n_in,
                              void* d_out, int out_size, void* d_ws, size_t ws_size,
                              hipStream_t stream) {
    const float* x    = (const float*)d_in[0];
    const int*   ei   = (const int*)d_in[1];
    const float* W1   = (const float*)d_in[2];
    const float* b1   = (const float*)d_in[3];
    const float* W2   = (const float*)d_in[4];
    const float* b2   = (const float*)d_in[5];
    const float* Wout = (const float*)d_in[6];
    const float* bout = (const float*)d_in[7];
    float*       out  = (float*)d_out;

    const int* src = ei;            // edge_index[0]
    const int* dst = ei + N_EDGES;  // edge_index[1]

    char* ws = (char*)d_ws;
    size_t off = 0;
    auto alloc = [&](size_t bytes) {
        size_t o = off;
        off = (off + bytes + 511) & ~(size_t)511;
        return (void*)(ws + o);
    };
    int*     counts4   = (int*)    alloc((size_t)N_NODES * 4 * sizeof(int));
    int4*    base4     = (int4*)   alloc((size_t)N_NODES * sizeof(int4));
    int*     row_start = (int*)    alloc((N_NODES + 1) * sizeof(int));
    float*   dinv      = (float*)  alloc(N_NODES * sizeof(float));
    int*     blk_sums  = (int*)    alloc(64 * sizeof(int));
    int*     rank      = (int*)    alloc((size_t)N_EDGES * sizeof(int));
    int*     csr_src   = (int*)    alloc((size_t)N_EDGES * sizeof(int));
    __half*  BT1       = (__half*) alloc((size_t)96 * 136 * sizeof(__half));
    __half*  BT2       = (__half*) alloc((size_t)96 * 136 * sizeof(__half));
    __half*  Th        = (__half*) alloc((size_t)N_NODES * 96 * sizeof(__half));
    __half*  Hh        = (__half*) alloc((size_t)N_NODES * 96 * sizeof(__half));

    const int NSCAN = (N_NODES + 1023) / 1024;   // 49
    const int CB    = (N_EDGES + 255) / 256;     // 3125
    const int GB    = (N_NODES + 63) / 64;       // 782

    // --- prep: zero counts4 + transpose weights (one launch) ---
    prep_kernel<<<ZB + WB, 256, 0, stream>>>(
        (int4*)counts4, W1, W2, BT1, BT2);

    // --- CSR: count (full occupancy) ---
    count_kernel<<<CB, 256, 0, stream>>>(dst, counts4, rank, N_EDGES);

    // --- layer-1 GEMM (depends only on prep) ---
    mfma_gemm_kernel<F_INN, float><<<GB, 256, 0, stream>>>(
        x, BT1, (float4*)Th, N_NODES);

    scan_local_kernel<<<NSCAN, 1024, 0, stream>>>(
        (const int4*)counts4, row_start, dinv, blk_sums, N_NODES);
    scan_apply_kernel<<<NSCAN, 1024, 0, stream>>>(
        row_start, blk_sums, (const int4*)counts4, base4, N_NODES, NSCAN);
    fill_csr_kernel<<<CB, 256, 0, stream>>>(
        src, dst, rank, (const int*)base4, csr_src, N_EDGES);

    // --- layer 1 aggregation -> H (fp16) ---
    agg_kernel<<<(N_NODES + 3) / 4, 256, 0, stream>>>(
        (const __half2*)Th, row_start, csr_src, dinv, b1, (__half2*)Hh, N_NODES);

    // --- layer 2: GEMM (fp16 in) + aggregation ---
    mfma_gemm_kernel<F_HID, __half><<<GB, 256, 0, stream>>>(
        Hh, BT2, (float4*)Th, N_NODES);
    agg_kernel<<<(N_NODES + 3) / 4, 256, 0, stream>>>(
        (const __half2*)Th, row_start, csr_src, dinv, b2, (__half2*)Hh, N_NODES);

    // --- output ---
    gemm_out_kernel<<<(N_NODES + 31) / 32, dim3(10, 32), 0, stream>>>(
        (const __half2*)Hh, Wout, bout, out, N_NODES);
}